// Round 5
// baseline (464.408 us; speedup 1.0000x reference)
//
#include <hip/hip_runtime.h>
#include <hip/hip_bf16.h>

typedef __attribute__((ext_vector_type(8))) short short8;
typedef __attribute__((ext_vector_type(4))) float f32x4;

#define EPS 1e-5f

__device__ __forceinline__ unsigned short f2bf(float f) {
    union { float f; unsigned u; } v; v.f = f;
    unsigned u = v.u;
    u += 0x7FFFu + ((u >> 16) & 1u);   // RNE
    return (unsigned short)(u >> 16);
}
__device__ __forceinline__ float bflo(unsigned u) {
    union { unsigned u; float f; } v; v.u = u << 16; return v.f;
}
__device__ __forceinline__ float bfhi(unsigned u) {
    union { unsigned u; float f; } v; v.u = u & 0xffff0000u; return v.f;
}
__device__ __forceinline__ float bf2f(ushort u) {
    union { unsigned u; float f; } v; v.u = ((unsigned)u) << 16; return v.f;
}

// ---------------- K0: one-time conversion f32 -> bf16 (weights + x) --------
// w1p/w2p get the within-32-chunk K-permutation sigma(p) = ((p&7)>>2)*16 +
// ((p>>3)&3)*4 + (p&3) so the FFN hidden dim can be consumed directly from
// MFMA accumulator registers (no LDS transpose anywhere).
__global__ __launch_bounds__(256) void k_prep(
        const float* __restrict__ ipw, const float* __restrict__ ow,
        const float* __restrict__ w1, const float* __restrict__ w2,
        const float* __restrict__ x,
        ushort* __restrict__ wqb, ushort* __restrict__ wob,
        ushort* __restrict__ w1p, ushort* __restrict__ w2p,
        ushort* __restrict__ xb, int nx) {
    int i = blockIdx.x * 256 + threadIdx.x;
    if (i < 49152) wqb[i] = f2bf(ipw[i]);
    if (i < 16384) wob[i] = f2bf(ow[i]);
    if (i < 65536) {
        int p = i & 31;
        int ps = (i & ~31) | ((((p & 7) >> 2) << 4) | (((p >> 3) & 3) << 2) | (p & 3));
        w1p[i] = f2bf(w1[ps]);
        w2p[i] = f2bf(w2[ps]);
    }
    int stride = gridDim.x * 256 * 4;
    for (int j = i * 4; j < nx; j += stride) {
        f32x4 v = *(const f32x4*)(x + j);
        uint2 o;
        o.x = (unsigned)f2bf(v[0]) | ((unsigned)f2bf(v[1]) << 16);
        o.y = (unsigned)f2bf(v[2]) | ((unsigned)f2bf(v[3]) << 16);
        *(uint2*)(xb + j) = o;
    }
}

// ---------------- K1: qkv = x @ in_proj_w^T + b  (swapped MFMA) ------------
// mfma(A=w_frag, B=x_frag): D[row = out-col = nt*16+l4*4+r][col = x-row = l16].
// Lane owns 4 consecutive out-cols of ONE row -> packed 8B stores.
__global__ __launch_bounds__(256) void k_qkv(
        const ushort* __restrict__ xb, const ushort* __restrict__ w,
        const float* __restrict__ bias, ushort* __restrict__ qkv, int N) {
    const int wave = threadIdx.x >> 6, lane = threadIdx.x & 63;
    const int l16 = lane & 15, l4 = lane >> 4;
    const int row = blockIdx.x * 64 + wave * 16 + l16;
    const int rc = row < N ? row : N - 1;
    const bool ok = row < N;

    short8 xf[4];
    #pragma unroll
    for (int c = 0; c < 4; ++c)
        xf[c] = *(const short8*)(xb + (size_t)rc*128 + c*32 + l4*8);

    #pragma unroll 4
    for (int nt = 0; nt < 24; ++nt) {
        f32x4 a = {0.f, 0.f, 0.f, 0.f};
        #pragma unroll
        for (int c = 0; c < 4; ++c) {
            short8 wf = *(const short8*)(w + (size_t)(nt*16 + l16)*128 + c*32 + l4*8);
            a = __builtin_amdgcn_mfma_f32_16x16x32_bf16(wf, xf[c], a, 0, 0, 0);
        }
        f32x4 bv = *(const f32x4*)(bias + nt*16 + l4*4);
        uint2 o;
        o.x = (unsigned)f2bf(a[0] + bv[0]) | ((unsigned)f2bf(a[1] + bv[1]) << 16);
        o.y = (unsigned)f2bf(a[2] + bv[2]) | ((unsigned)f2bf(a[3] + bv[3]) << 16);
        if (ok) *(uint2*)(qkv + (size_t)row*384 + nt*16 + l4*4) = o;
    }
}

// ---------------- K2: sampled attention; ctx written into dead Q region ----
// (unchanged from round 3 — 112us, gather-BW bound)
__global__ __launch_bounds__(256) void k_attn(
        ushort* __restrict__ qkv, const int* __restrict__ samp, int N) {
    __shared__ float aw[4][8][17];              // [wave][head][k], padded
    __shared__ int   ai[4][16];                 // [wave][k] sample idx
    const int wave = threadIdx.x >> 6, lane = threadIdx.x & 63;
    const int n = blockIdx.x * 4 + wave;
    if (n >= N) return;
    const int k  = lane & 15;
    const int hp = lane >> 4;
    const int h0 = hp, h1 = hp + 4;

    const int idx = samp[(size_t)n*16 + k];
    const ushort* qrow = qkv + (size_t)n*384;
    const ushort* krow = qkv + (size_t)idx*384 + 128;

    float s0 = 0.f, s1 = 0.f;
    {
        const uint4* qa = (const uint4*)(qrow + h0*16);
        const uint4* ka = (const uint4*)(krow + h0*16);
        const uint4* qb = (const uint4*)(qrow + h1*16);
        const uint4* kb = (const uint4*)(krow + h1*16);
        #pragma unroll
        for (int i = 0; i < 2; ++i) {
            uint4 ua = qa[i], va = ka[i], ub = qb[i], vb = kb[i];
            s0 += bflo(ua.x)*bflo(va.x) + bfhi(ua.x)*bfhi(va.x)
                + bflo(ua.y)*bflo(va.y) + bfhi(ua.y)*bfhi(va.y)
                + bflo(ua.z)*bflo(va.z) + bfhi(ua.z)*bfhi(va.z)
                + bflo(ua.w)*bflo(va.w) + bfhi(ua.w)*bfhi(va.w);
            s1 += bflo(ub.x)*bflo(vb.x) + bfhi(ub.x)*bfhi(vb.x)
                + bflo(ub.y)*bflo(vb.y) + bfhi(ub.y)*bfhi(vb.y)
                + bflo(ub.z)*bflo(vb.z) + bfhi(ub.z)*bfhi(vb.z)
                + bflo(ub.w)*bflo(vb.w) + bfhi(ub.w)*bfhi(vb.w);
        }
    }
    s0 *= 0.25f; s1 *= 0.25f;     // 1/sqrt(16)
    float m0 = s0, m1 = s1;
    #pragma unroll
    for (int off = 1; off < 16; off <<= 1) {
        m0 = fmaxf(m0, __shfl_xor(m0, off));
        m1 = fmaxf(m1, __shfl_xor(m1, off));
    }
    float e0 = __expf(s0 - m0), e1 = __expf(s1 - m1);
    float d0 = e0, d1 = e1;
    #pragma unroll
    for (int off = 1; off < 16; off <<= 1) {
        d0 += __shfl_xor(d0, off);
        d1 += __shfl_xor(d1, off);
    }
    aw[wave][h0][k] = e0 / d0;
    aw[wave][h1][k] = e1 / d1;
    if (hp == 0) ai[wave][k] = idx;

    // ---- phase 2 ----
    const int c = lane & 15;        // 16B chunk of the 256B V row
    const int g = lane >> 4;        // k-group
    const int h = c >> 1;           // head owning dims c*8..c*8+7
    const ushort* vt = qkv + 256;   // V region base

    int rows[4];
    #pragma unroll
    for (int b = 0; b < 4; ++b) rows[b] = ai[wave][g + b*4];
    uint4 vv[4];
    #pragma unroll
    for (int b = 0; b < 4; ++b)
        vv[b] = *(const uint4*)(vt + (size_t)(unsigned)rows[b]*384 + c*8);
    float wk[4];
    #pragma unroll
    for (int b = 0; b < 4; ++b) wk[b] = aw[wave][h][g + b*4];

    float a8[8] = {0.f,0.f,0.f,0.f,0.f,0.f,0.f,0.f};
    #pragma unroll
    for (int b = 0; b < 4; ++b) {
        a8[0] = fmaf(wk[b], bflo(vv[b].x), a8[0]);
        a8[1] = fmaf(wk[b], bfhi(vv[b].x), a8[1]);
        a8[2] = fmaf(wk[b], bflo(vv[b].y), a8[2]);
        a8[3] = fmaf(wk[b], bfhi(vv[b].y), a8[3]);
        a8[4] = fmaf(wk[b], bflo(vv[b].z), a8[4]);
        a8[5] = fmaf(wk[b], bfhi(vv[b].z), a8[5]);
        a8[6] = fmaf(wk[b], bflo(vv[b].w), a8[6]);
        a8[7] = fmaf(wk[b], bfhi(vv[b].w), a8[7]);
    }
    #pragma unroll
    for (int i = 0; i < 8; ++i) {
        a8[i] += __shfl_xor(a8[i], 16);
        a8[i] += __shfl_xor(a8[i], 32);
    }
    if (lane < 16) {
        uint4 pack;
        pack.x = (unsigned)f2bf(a8[0]) | ((unsigned)f2bf(a8[1]) << 16);
        pack.y = (unsigned)f2bf(a8[2]) | ((unsigned)f2bf(a8[3]) << 16);
        pack.z = (unsigned)f2bf(a8[4]) | ((unsigned)f2bf(a8[5]) << 16);
        pack.w = (unsigned)f2bf(a8[6]) | ((unsigned)f2bf(a8[7]) << 16);
        *(uint4*)(qkv + (size_t)n*384 + c*8) = pack;   // ctx into dead Q region
    }
}

// ---------------- K3: fused tail, LDS-free / barrier-free ----------------
// All MFMAs operand-swapped: D[row = lane's own token row l16][cols l4*4+r].
// LN1/LN2 = 2x shfl_xor. Stage1 output feeds stage2 A-frag in registers via
// the sigma permutation pre-baked into w1p/w2p. Zero LDS, zero barriers.
__global__ __launch_bounds__(256) void k_tail(
        const ushort* __restrict__ ctx, const ushort* __restrict__ wob,
        const float* __restrict__ ob, const ushort* __restrict__ xb,
        const float* __restrict__ g1, const float* __restrict__ be1,
        const ushort* __restrict__ w1p, const float* __restrict__ b1,
        const ushort* __restrict__ w2p, const float* __restrict__ b2,
        const float* __restrict__ g2, const float* __restrict__ be2,
        float* __restrict__ out, int N) {
    const int wave = threadIdx.x >> 6, lane = threadIdx.x & 63;
    const int l16 = lane & 15, l4 = lane >> 4;
    const int row = blockIdx.x * 64 + wave * 16 + l16;
    const int rc = row < N ? row : N - 1;

    // ---- ctx fragments (lane's own row) ----
    short8 cf[4];
    #pragma unroll
    for (int c = 0; c < 4; ++c)
        cf[c] = *(const short8*)(ctx + (size_t)rc*384 + c*32 + l4*8);

    // ---- out-proj (swapped) + bias + x residual ----
    float yv[8][4];
    float sum = 0.f, sq = 0.f;
    #pragma unroll
    for (int nt = 0; nt < 8; ++nt) {
        f32x4 a = {0.f, 0.f, 0.f, 0.f};
        #pragma unroll
        for (int c = 0; c < 4; ++c) {
            short8 wf = *(const short8*)(wob + (size_t)(nt*16 + l16)*128 + c*32 + l4*8);
            a = __builtin_amdgcn_mfma_f32_16x16x32_bf16(wf, cf[c], a, 0, 0, 0);
        }
        f32x4 obv = *(const f32x4*)(ob + nt*16 + l4*4);
        uint2 xr = *(const uint2*)(xb + (size_t)rc*128 + nt*16 + l4*4);
        yv[nt][0] = a[0] + obv[0] + bflo(xr.x);
        yv[nt][1] = a[1] + obv[1] + bfhi(xr.x);
        yv[nt][2] = a[2] + obv[2] + bflo(xr.y);
        yv[nt][3] = a[3] + obv[3] + bfhi(xr.y);
        #pragma unroll
        for (int r = 0; r < 4; ++r) { sum += yv[nt][r]; sq += yv[nt][r]*yv[nt][r]; }
    }
    sum += __shfl_xor(sum, 16); sum += __shfl_xor(sum, 32);
    sq  += __shfl_xor(sq, 16);  sq  += __shfl_xor(sq, 32);
    float mean = sum * (1.f/128.f);
    float rstd = rsqrtf(sq*(1.f/128.f) - mean*mean + EPS);

    // ---- LN1 -> packed bf16 y fragments (B-operand k-order = sigma) ----
    short8 yfrag[4];
    #pragma unroll
    for (int nt = 0; nt < 8; ++nt) {
        f32x4 gv = *(const f32x4*)(g1 + nt*16 + l4*4);
        f32x4 bv = *(const f32x4*)(be1 + nt*16 + l4*4);
        #pragma unroll
        for (int r = 0; r < 4; ++r) {
            float yn = (yv[nt][r] - mean) * rstd * gv[r] + bv[r];
            yfrag[nt >> 1][(nt & 1)*4 + r] = (short)f2bf(yn);
        }
    }

    // ---- FFN: per kb, stage1 (2 hidden tiles) -> relu -> stage2, in regs ----
    f32x4 acc2[8];
    #pragma unroll
    for (int nt = 0; nt < 8; ++nt) acc2[nt] = (f32x4){0.f,0.f,0.f,0.f};

    #pragma unroll 2
    for (int kb = 0; kb < 16; ++kb) {
        f32x4 hA = {0.f,0.f,0.f,0.f}, hB = {0.f,0.f,0.f,0.f};
        #pragma unroll
        for (int c = 0; c < 4; ++c) {
            short8 wA = *(const short8*)(w1p + (size_t)(kb*32 + l16)*128 + c*32 + l4*8);
            short8 wB = *(const short8*)(w1p + (size_t)(kb*32 + 16 + l16)*128 + c*32 + l4*8);
            hA = __builtin_amdgcn_mfma_f32_16x16x32_bf16(wA, yfrag[c], hA, 0, 0, 0);
            hB = __builtin_amdgcn_mfma_f32_16x16x32_bf16(wB, yfrag[c], hB, 0, 0, 0);
        }
        f32x4 bA = *(const f32x4*)(b1 + kb*32 + l4*4);
        f32x4 bB = *(const f32x4*)(b1 + kb*32 + 16 + l4*4);
        short8 hf;
        #pragma unroll
        for (int r = 0; r < 4; ++r) {
            float vA = hA[r] + bA[r]; vA = vA > 0.f ? vA : 0.f;
            float vB = hB[r] + bB[r]; vB = vB > 0.f ? vB : 0.f;
            hf[r]     = (short)f2bf(vA);
            hf[4 + r] = (short)f2bf(vB);
        }
        #pragma unroll
        for (int nt = 0; nt < 8; ++nt) {
            short8 w2f = *(const short8*)(w2p + (size_t)(nt*16 + l16)*512 + kb*32 + l4*8);
            acc2[nt] = __builtin_amdgcn_mfma_f32_16x16x32_bf16(w2f, hf, acc2[nt], 0, 0, 0);
        }
    }

    // ---- s = y + ff + b2 (in-place in acc2), LN2, coalesced float4 out ----
    float sum2 = 0.f, sq2 = 0.f;
    #pragma unroll
    for (int nt = 0; nt < 8; ++nt) {
        f32x4 b2v = *(const f32x4*)(b2 + nt*16 + l4*4);
        #pragma unroll
        for (int r = 0; r < 4; ++r) {
            float s = bf2f((ushort)yfrag[nt >> 1][(nt & 1)*4 + r]) + acc2[nt][r] + b2v[r];
            acc2[nt][r] = s; sum2 += s; sq2 += s*s;
        }
    }
    sum2 += __shfl_xor(sum2, 16); sum2 += __shfl_xor(sum2, 32);
    sq2  += __shfl_xor(sq2, 16);  sq2  += __shfl_xor(sq2, 32);
    float mean2 = sum2 * (1.f/128.f);
    float rstd2 = rsqrtf(sq2*(1.f/128.f) - mean2*mean2 + EPS);
    if (row < N) {
        #pragma unroll
        for (int nt = 0; nt < 8; ++nt) {
            f32x4 gv = *(const f32x4*)(g2 + nt*16 + l4*4);
            f32x4 bv = *(const f32x4*)(be2 + nt*16 + l4*4);
            f32x4 o;
            #pragma unroll
            for (int r = 0; r < 4; ++r)
                o[r] = (acc2[nt][r] - mean2) * rstd2 * gv[r] + bv[r];
            *(f32x4*)(out + (size_t)row*128 + nt*16 + l4*4) = o;
        }
    }
}

extern "C" void kernel_launch(void* const* d_in, const int* in_sizes, int n_in,
                              void* d_out, int out_size, void* d_ws, size_t ws_size,
                              hipStream_t stream) {
    (void)n_in; (void)out_size; (void)ws_size;
    const float* x   = (const float*)d_in[0];
    const int*   smp = (const int*)  d_in[1];
    const float* ipw = (const float*)d_in[2];
    const float* ipb = (const float*)d_in[3];
    const float* ow  = (const float*)d_in[4];
    const float* ob  = (const float*)d_in[5];
    const float* w1  = (const float*)d_in[6];
    const float* b1  = (const float*)d_in[7];
    const float* w2  = (const float*)d_in[8];
    const float* b2  = (const float*)d_in[9];
    const float* g1  = (const float*)d_in[10];
    const float* be1 = (const float*)d_in[11];
    const float* g2  = (const float*)d_in[12];
    const float* be2 = (const float*)d_in[13];
    const int N = in_sizes[0] / 128;

    ushort* qkv  = (ushort*)d_ws;                   // [N][384] bf16; Q region reused as ctx
    ushort* wqb  = qkv + (size_t)N * 384;           // 384*128
    ushort* wob  = wqb + 384*128;                   // 128*128
    ushort* w1p  = wob + 128*128;                   // 512*128 (sigma-permuted K)
    ushort* w2p  = w1p + 512*128;                   // 128*512 (sigma-permuted K)
    ushort* xb   = w2p + 128*512;                   // [N][128] bf16 x
    float*  outp = (float*)d_out;

    const int nb = (N + 63) / 64;
    k_prep <<<12500,     256, 0, stream>>>(ipw, ow, w1, w2, x, wqb, wob, w1p, w2p, xb, N*128);
    k_qkv  <<<nb,        256, 0, stream>>>(xb, wqb, ipb, qkv, N);
    k_attn <<<(N+3)/4,   256, 0, stream>>>(qkv, smp, N);
    k_tail <<<nb,        256, 0, stream>>>(qkv, wob, ob, xb, g1, be1,
                                           w1p, b1, w2p, b2, g2, be2, outp, N);
}

// Round 6
// 339.391 us; speedup vs baseline: 1.3684x; 1.3684x over previous
//
#include <hip/hip_runtime.h>
#include <hip/hip_bf16.h>

typedef __attribute__((ext_vector_type(8))) short short8;
typedef __attribute__((ext_vector_type(4))) float f32x4;

#define EPS 1e-5f

__device__ __forceinline__ unsigned short f2bf(float f) {
    union { float f; unsigned u; } v; v.f = f;
    unsigned u = v.u;
    u += 0x7FFFu + ((u >> 16) & 1u);   // RNE
    return (unsigned short)(u >> 16);
}
__device__ __forceinline__ float bflo(unsigned u) {
    union { unsigned u; float f; } v; v.u = u << 16; return v.f;
}
__device__ __forceinline__ float bfhi(unsigned u) {
    union { unsigned u; float f; } v; v.u = u & 0xffff0000u; return v.f;
}
__device__ __forceinline__ float bf2f(ushort u) {
    union { unsigned u; float f; } v; v.u = ((unsigned)u) << 16; return v.f;
}

// load 8 consecutive f32, convert to a bf16x8 MFMA fragment
__device__ __forceinline__ short8 load_frag_f32(const float* __restrict__ p) {
    f32x4 a = *(const f32x4*)p;
    f32x4 b = *(const f32x4*)(p + 4);
    short8 r;
    r[0] = (short)f2bf(a[0]); r[1] = (short)f2bf(a[1]);
    r[2] = (short)f2bf(a[2]); r[3] = (short)f2bf(a[3]);
    r[4] = (short)f2bf(b[0]); r[5] = (short)f2bf(b[1]);
    r[6] = (short)f2bf(b[2]); r[7] = (short)f2bf(b[3]);
    return r;
}

// ---------------- K0: one-time conversion f32 -> bf16 (weights + x) --------
// w1p/w2p get the within-32-chunk K-permutation sigma(p) = ((p&7)>>2)*16 +
// ((p>>3)&3)*4 + (p&3) so the FFN hidden dim is consumed directly from MFMA
// accumulator registers (no transpose anywhere).
__global__ __launch_bounds__(256) void k_prep(
        const float* __restrict__ ipw, const float* __restrict__ ow,
        const float* __restrict__ w1, const float* __restrict__ w2,
        const float* __restrict__ x,
        ushort* __restrict__ wqb, ushort* __restrict__ wob,
        ushort* __restrict__ w1p, ushort* __restrict__ w2p,
        ushort* __restrict__ xb, int nx) {
    int i = blockIdx.x * 256 + threadIdx.x;
    if (i < 49152) wqb[i] = f2bf(ipw[i]);
    if (i < 16384) wob[i] = f2bf(ow[i]);
    if (i < 65536) {
        int p = i & 31;
        int ps = (i & ~31) | ((((p & 7) >> 2) << 4) | (((p >> 3) & 3) << 2) | (p & 3));
        w1p[i] = f2bf(w1[ps]);
        w2p[i] = f2bf(w2[ps]);
    }
    int stride = gridDim.x * 256 * 4;
    for (int j = i * 4; j < nx; j += stride) {
        f32x4 v = *(const f32x4*)(x + j);
        uint2 o;
        o.x = (unsigned)f2bf(v[0]) | ((unsigned)f2bf(v[1]) << 16);
        o.y = (unsigned)f2bf(v[2]) | ((unsigned)f2bf(v[3]) << 16);
        *(uint2*)(xb + j) = o;
    }
}

// ---------------- K1: qkv = x @ in_proj_w^T + b  (R4 form, measured OK) ----
__global__ __launch_bounds__(256) void k_qkv(
        const ushort* __restrict__ xb, const ushort* __restrict__ w,
        const float* __restrict__ bias, ushort* __restrict__ qkv, int N) {
    const int wave = threadIdx.x >> 6, lane = threadIdx.x & 63;
    const int l16 = lane & 15, l4 = lane >> 4;
    const int base = blockIdx.x * 64;

    short8 af[4][4];
    #pragma unroll
    for (int mt = 0; mt < 4; ++mt) {
        int row = base + mt*16 + l16;
        int rc = row < N ? row : N - 1;
        const ushort* p = xb + (size_t)rc*128 + l4*8;
        #pragma unroll
        for (int kb = 0; kb < 4; ++kb) af[mt][kb] = *(const short8*)(p + kb*32);
    }
    #pragma unroll
    for (int i = 0; i < 6; ++i) {
        int col = (wave*6 + i)*16 + l16;
        const ushort* pw = w + (size_t)col*128 + l4*8;
        short8 bf[4];
        #pragma unroll
        for (int kb = 0; kb < 4; ++kb) bf[kb] = *(const short8*)(pw + kb*32);
        float bv = bias[col];
        #pragma unroll
        for (int mt = 0; mt < 4; ++mt) {
            f32x4 acc = {0.f, 0.f, 0.f, 0.f};
            #pragma unroll
            for (int kb = 0; kb < 4; ++kb)
                acc = __builtin_amdgcn_mfma_f32_16x16x32_bf16(af[mt][kb], bf[kb], acc, 0, 0, 0);
            #pragma unroll
            for (int r = 0; r < 4; ++r) {
                int row = base + mt*16 + l4*4 + r;
                if (row < N) qkv[(size_t)row*384 + col] = f2bf(acc[r] + bv);
            }
        }
    }
}

// ---------------- K2: sampled attention (unchanged, gather-bound) ----------
__global__ __launch_bounds__(256) void k_attn(
        ushort* __restrict__ qkv, const int* __restrict__ samp, int N) {
    __shared__ float aw[4][8][17];              // [wave][head][k], padded
    __shared__ int   ai[4][16];                 // [wave][k] sample idx
    const int wave = threadIdx.x >> 6, lane = threadIdx.x & 63;
    const int n = blockIdx.x * 4 + wave;
    if (n >= N) return;
    const int k  = lane & 15;
    const int hp = lane >> 4;
    const int h0 = hp, h1 = hp + 4;

    const int idx = samp[(size_t)n*16 + k];
    const ushort* qrow = qkv + (size_t)n*384;
    const ushort* krow = qkv + (size_t)idx*384 + 128;

    float s0 = 0.f, s1 = 0.f;
    {
        const uint4* qa = (const uint4*)(qrow + h0*16);
        const uint4* ka = (const uint4*)(krow + h0*16);
        const uint4* qb = (const uint4*)(qrow + h1*16);
        const uint4* kb = (const uint4*)(krow + h1*16);
        #pragma unroll
        for (int i = 0; i < 2; ++i) {
            uint4 ua = qa[i], va = ka[i], ub = qb[i], vb = kb[i];
            s0 += bflo(ua.x)*bflo(va.x) + bfhi(ua.x)*bfhi(va.x)
                + bflo(ua.y)*bflo(va.y) + bfhi(ua.y)*bfhi(va.y)
                + bflo(ua.z)*bflo(va.z) + bfhi(ua.z)*bfhi(va.z)
                + bflo(ua.w)*bflo(va.w) + bfhi(ua.w)*bfhi(va.w);
            s1 += bflo(ub.x)*bflo(vb.x) + bfhi(ub.x)*bfhi(vb.x)
                + bflo(ub.y)*bflo(vb.y) + bfhi(ub.y)*bfhi(vb.y)
                + bflo(ub.z)*bflo(vb.z) + bfhi(ub.z)*bfhi(vb.z)
                + bflo(ub.w)*bflo(vb.w) + bfhi(ub.w)*bfhi(vb.w);
        }
    }
    s0 *= 0.25f; s1 *= 0.25f;     // 1/sqrt(16)
    float m0 = s0, m1 = s1;
    #pragma unroll
    for (int off = 1; off < 16; off <<= 1) {
        m0 = fmaxf(m0, __shfl_xor(m0, off));
        m1 = fmaxf(m1, __shfl_xor(m1, off));
    }
    float e0 = __expf(s0 - m0), e1 = __expf(s1 - m1);
    float d0 = e0, d1 = e1;
    #pragma unroll
    for (int off = 1; off < 16; off <<= 1) {
        d0 += __shfl_xor(d0, off);
        d1 += __shfl_xor(d1, off);
    }
    aw[wave][h0][k] = e0 / d0;
    aw[wave][h1][k] = e1 / d1;
    if (hp == 0) ai[wave][k] = idx;

    // ---- phase 2 ----
    const int c = lane & 15;        // 16B chunk of the 256B V row
    const int g = lane >> 4;        // k-group
    const int h = c >> 1;           // head owning dims c*8..c*8+7
    const ushort* vt = qkv + 256;   // V region base

    int rows[4];
    #pragma unroll
    for (int b = 0; b < 4; ++b) rows[b] = ai[wave][g + b*4];
    uint4 vv[4];
    #pragma unroll
    for (int b = 0; b < 4; ++b)
        vv[b] = *(const uint4*)(vt + (size_t)(unsigned)rows[b]*384 + c*8);
    float wk[4];
    #pragma unroll
    for (int b = 0; b < 4; ++b) wk[b] = aw[wave][h][g + b*4];

    float a8[8] = {0.f,0.f,0.f,0.f,0.f,0.f,0.f,0.f};
    #pragma unroll
    for (int b = 0; b < 4; ++b) {
        a8[0] = fmaf(wk[b], bflo(vv[b].x), a8[0]);
        a8[1] = fmaf(wk[b], bfhi(vv[b].x), a8[1]);
        a8[2] = fmaf(wk[b], bflo(vv[b].y), a8[2]);
        a8[3] = fmaf(wk[b], bfhi(vv[b].y), a8[3]);
        a8[4] = fmaf(wk[b], bflo(vv[b].z), a8[4]);
        a8[5] = fmaf(wk[b], bfhi(vv[b].z), a8[5]);
        a8[6] = fmaf(wk[b], bflo(vv[b].w), a8[6]);
        a8[7] = fmaf(wk[b], bfhi(vv[b].w), a8[7]);
    }
    #pragma unroll
    for (int i = 0; i < 8; ++i) {
        a8[i] += __shfl_xor(a8[i], 16);
        a8[i] += __shfl_xor(a8[i], 32);
    }
    if (lane < 16) {
        uint4 pack;
        pack.x = (unsigned)f2bf(a8[0]) | ((unsigned)f2bf(a8[1]) << 16);
        pack.y = (unsigned)f2bf(a8[2]) | ((unsigned)f2bf(a8[3]) << 16);
        pack.z = (unsigned)f2bf(a8[4]) | ((unsigned)f2bf(a8[5]) << 16);
        pack.w = (unsigned)f2bf(a8[6]) | ((unsigned)f2bf(a8[7]) << 16);
        *(uint4*)(qkv + (size_t)n*384 + c*8) = pack;   // ctx into dead Q region
    }
}

// ---------------- K3: fused tail, mt=2 rows/wave, register-resident --------
// Swapped MFMAs (D row = lane's token row l16). Each weight fragment load
// feeds 2 MFMAs (two 16-row tiles). Zero LDS, zero barriers. acc2 -> AGPRs.
__global__ __launch_bounds__(256) void k_tail(
        const ushort* __restrict__ ctx, const ushort* __restrict__ wob,
        const float* __restrict__ ob, const ushort* __restrict__ xb,
        const float* __restrict__ g1, const float* __restrict__ be1,
        const ushort* __restrict__ w1p, const float* __restrict__ b1,
        const ushort* __restrict__ w2p, const float* __restrict__ b2,
        const float* __restrict__ g2, const float* __restrict__ be2,
        float* __restrict__ out, int N) {
    const int wave = threadIdx.x >> 6, lane = threadIdx.x & 63;
    const int l16 = lane & 15, l4 = lane >> 4;
    const int base = blockIdx.x * 128 + wave * 32;
    int row[2], rc[2];
    row[0] = base + l16;       rc[0] = row[0] < N ? row[0] : N - 1;
    row[1] = base + 16 + l16;  rc[1] = row[1] < N ? row[1] : N - 1;

    // ---- ctx fragments for both row tiles ----
    short8 cf[2][4];
    #pragma unroll
    for (int mt = 0; mt < 2; ++mt)
        #pragma unroll
        for (int c = 0; c < 4; ++c)
            cf[mt][c] = *(const short8*)(ctx + (size_t)rc[mt]*384 + c*32 + l4*8);

    // ---- out-proj (swapped) + bias + x residual ----
    f32x4 yv[2][8];
    float sum0 = 0.f, sq0 = 0.f, sum1 = 0.f, sq1 = 0.f;
    #pragma unroll
    for (int nt = 0; nt < 8; ++nt) {
        f32x4 a0 = {0.f,0.f,0.f,0.f}, a1 = {0.f,0.f,0.f,0.f};
        #pragma unroll
        for (int c = 0; c < 4; ++c) {
            short8 wf = *(const short8*)(wob + (size_t)(nt*16 + l16)*128 + c*32 + l4*8);
            a0 = __builtin_amdgcn_mfma_f32_16x16x32_bf16(wf, cf[0][c], a0, 0, 0, 0);
            a1 = __builtin_amdgcn_mfma_f32_16x16x32_bf16(wf, cf[1][c], a1, 0, 0, 0);
        }
        f32x4 obv = *(const f32x4*)(ob + nt*16 + l4*4);
        uint2 xr0 = *(const uint2*)(xb + (size_t)rc[0]*128 + nt*16 + l4*4);
        uint2 xr1 = *(const uint2*)(xb + (size_t)rc[1]*128 + nt*16 + l4*4);
        yv[0][nt][0] = a0[0] + obv[0] + bflo(xr0.x);
        yv[0][nt][1] = a0[1] + obv[1] + bfhi(xr0.x);
        yv[0][nt][2] = a0[2] + obv[2] + bflo(xr0.y);
        yv[0][nt][3] = a0[3] + obv[3] + bfhi(xr0.y);
        yv[1][nt][0] = a1[0] + obv[0] + bflo(xr1.x);
        yv[1][nt][1] = a1[1] + obv[1] + bfhi(xr1.x);
        yv[1][nt][2] = a1[2] + obv[2] + bflo(xr1.y);
        yv[1][nt][3] = a1[3] + obv[3] + bfhi(xr1.y);
        #pragma unroll
        for (int r = 0; r < 4; ++r) {
            sum0 += yv[0][nt][r]; sq0 += yv[0][nt][r]*yv[0][nt][r];
            sum1 += yv[1][nt][r]; sq1 += yv[1][nt][r]*yv[1][nt][r];
        }
    }
    sum0 += __shfl_xor(sum0, 16); sum0 += __shfl_xor(sum0, 32);
    sq0  += __shfl_xor(sq0, 16);  sq0  += __shfl_xor(sq0, 32);
    sum1 += __shfl_xor(sum1, 16); sum1 += __shfl_xor(sum1, 32);
    sq1  += __shfl_xor(sq1, 16);  sq1  += __shfl_xor(sq1, 32);
    float mean[2], rstd[2];
    mean[0] = sum0 * (1.f/128.f);
    rstd[0] = rsqrtf(sq0*(1.f/128.f) - mean[0]*mean[0] + EPS);
    mean[1] = sum1 * (1.f/128.f);
    rstd[1] = rsqrtf(sq1*(1.f/128.f) - mean[1]*mean[1] + EPS);

    // ---- LN1 -> packed bf16 y fragments (k-order = sigma) ----
    short8 yfrag[2][4];
    #pragma unroll
    for (int nt = 0; nt < 8; ++nt) {
        f32x4 gv = *(const f32x4*)(g1 + nt*16 + l4*4);
        f32x4 bv = *(const f32x4*)(be1 + nt*16 + l4*4);
        #pragma unroll
        for (int mt = 0; mt < 2; ++mt)
            #pragma unroll
            for (int r = 0; r < 4; ++r) {
                float yn = (yv[mt][nt][r] - mean[mt]) * rstd[mt] * gv[r] + bv[r];
                yfrag[mt][nt >> 1][(nt & 1)*4 + r] = (short)f2bf(yn);
            }
    }

    // ---- FFN: per kb {16 loads up front -> 16 s1 MFMA -> relu -> 16 s2 MFMA} ----
    f32x4 acc2[2][8];
    #pragma unroll
    for (int mt = 0; mt < 2; ++mt)
        #pragma unroll
        for (int nt = 0; nt < 8; ++nt) acc2[mt][nt] = (f32x4){0.f,0.f,0.f,0.f};

    #pragma unroll 2
    for (int kb = 0; kb < 16; ++kb) {
        short8 wA[4], wB[4], w2f[8];
        #pragma unroll
        for (int c = 0; c < 4; ++c) {
            wA[c] = *(const short8*)(w1p + (size_t)(kb*32 + l16)*128 + c*32 + l4*8);
            wB[c] = *(const short8*)(w1p + (size_t)(kb*32 + 16 + l16)*128 + c*32 + l4*8);
        }
        #pragma unroll
        for (int nt = 0; nt < 8; ++nt)
            w2f[nt] = *(const short8*)(w2p + (size_t)(nt*16 + l16)*512 + kb*32 + l4*8);

        f32x4 hA[2] = {{0.f,0.f,0.f,0.f},{0.f,0.f,0.f,0.f}};
        f32x4 hB[2] = {{0.f,0.f,0.f,0.f},{0.f,0.f,0.f,0.f}};
        #pragma unroll
        for (int c = 0; c < 4; ++c) {
            #pragma unroll
            for (int mt = 0; mt < 2; ++mt) {
                hA[mt] = __builtin_amdgcn_mfma_f32_16x16x32_bf16(wA[c], yfrag[mt][c], hA[mt], 0, 0, 0);
                hB[mt] = __builtin_amdgcn_mfma_f32_16x16x32_bf16(wB[c], yfrag[mt][c], hB[mt], 0, 0, 0);
            }
        }
        f32x4 bA = *(const f32x4*)(b1 + kb*32 + l4*4);
        f32x4 bB = *(const f32x4*)(b1 + kb*32 + 16 + l4*4);
        short8 hf[2];
        #pragma unroll
        for (int mt = 0; mt < 2; ++mt)
            #pragma unroll
            for (int r = 0; r < 4; ++r) {
                float vA = hA[mt][r] + bA[r]; vA = vA > 0.f ? vA : 0.f;
                float vB = hB[mt][r] + bB[r]; vB = vB > 0.f ? vB : 0.f;
                hf[mt][r]     = (short)f2bf(vA);
                hf[mt][4 + r] = (short)f2bf(vB);
            }
        #pragma unroll
        for (int nt = 0; nt < 8; ++nt) {
            acc2[0][nt] = __builtin_amdgcn_mfma_f32_16x16x32_bf16(w2f[nt], hf[0], acc2[0][nt], 0, 0, 0);
            acc2[1][nt] = __builtin_amdgcn_mfma_f32_16x16x32_bf16(w2f[nt], hf[1], acc2[1][nt], 0, 0, 0);
        }
    }

    // ---- s = y + ff + b2, LN2, coalesced float4 out ----
    #pragma unroll
    for (int mt = 0; mt < 2; ++mt) {
        float sum2 = 0.f, sq2 = 0.f;
        #pragma unroll
        for (int nt = 0; nt < 8; ++nt) {
            f32x4 b2v = *(const f32x4*)(b2 + nt*16 + l4*4);
            #pragma unroll
            for (int r = 0; r < 4; ++r) {
                float s = bf2f((ushort)yfrag[mt][nt >> 1][(nt & 1)*4 + r]) + acc2[mt][nt][r] + b2v[r];
                acc2[mt][nt][r] = s; sum2 += s; sq2 += s*s;
            }
        }
        sum2 += __shfl_xor(sum2, 16); sum2 += __shfl_xor(sum2, 32);
        sq2  += __shfl_xor(sq2, 16);  sq2  += __shfl_xor(sq2, 32);
        float mean2 = sum2 * (1.f/128.f);
        float rstd2 = rsqrtf(sq2*(1.f/128.f) - mean2*mean2 + EPS);
        if (row[mt] < N) {
            #pragma unroll
            for (int nt = 0; nt < 8; ++nt) {
                f32x4 gv = *(const f32x4*)(g2 + nt*16 + l4*4);
                f32x4 bv = *(const f32x4*)(be2 + nt*16 + l4*4);
                f32x4 o;
                #pragma unroll
                for (int r = 0; r < 4; ++r)
                    o[r] = (acc2[mt][nt][r] - mean2) * rstd2 * gv[r] + bv[r];
                *(f32x4*)(out + (size_t)row[mt]*128 + nt*16 + l4*4) = o;
            }
        }
    }
}

extern "C" void kernel_launch(void* const* d_in, const int* in_sizes, int n_in,
                              void* d_out, int out_size, void* d_ws, size_t ws_size,
                              hipStream_t stream) {
    (void)n_in; (void)out_size; (void)ws_size;
    const float* x   = (const float*)d_in[0];
    const int*   smp = (const int*)  d_in[1];
    const float* ipw = (const float*)d_in[2];
    const float* ipb = (const float*)d_in[3];
    const float* ow  = (const float*)d_in[4];
    const float* ob  = (const float*)d_in[5];
    const float* w1  = (const float*)d_in[6];
    const float* b1  = (const float*)d_in[7];
    const float* w2  = (const float*)d_in[8];
    const float* b2  = (const float*)d_in[9];
    const float* g1  = (const float*)d_in[10];
    const float* be1 = (const float*)d_in[11];
    const float* g2  = (const float*)d_in[12];
    const float* be2 = (const float*)d_in[13];
    const int N = in_sizes[0] / 128;

    ushort* qkv  = (ushort*)d_ws;                   // [N][384] bf16; Q region reused as ctx
    ushort* wqb  = qkv + (size_t)N * 384;           // 384*128
    ushort* wob  = wqb + 384*128;                   // 128*128
    ushort* w1p  = wob + 128*128;                   // 512*128 (sigma-permuted K)
    ushort* w2p  = w1p + 512*128;                   // 128*512 (sigma-permuted K)
    ushort* xb   = w2p + 128*512;                   // [N][128] bf16 x
    float*  outp = (float*)d_out;

    const int nb = (N + 63) / 64;
    k_prep <<<12500,       256, 0, stream>>>(ipw, ow, w1, w2, x, wqb, wob, w1p, w2p, xb, N*128);
    k_qkv  <<<nb,          256, 0, stream>>>(xb, wqb, ipb, qkv, N);
    k_attn <<<(N+3)/4,     256, 0, stream>>>(qkv, smp, N);
    k_tail <<<(N+127)/128, 256, 0, stream>>>(qkv, wob, ob, xb, g1, be1,
                                             w1p, b1, w2p, b2, g2, be2, outp, N);
}

// Round 7
// 267.477 us; speedup vs baseline: 1.7363x; 1.2689x over previous
//
#include <hip/hip_runtime.h>
#include <hip/hip_bf16.h>

typedef __attribute__((ext_vector_type(8))) short short8;
typedef __attribute__((ext_vector_type(4))) float f32x4;

#define EPS 1e-5f

__device__ __forceinline__ unsigned short f2bf(float f) {
    union { float f; unsigned u; } v; v.f = f;
    unsigned u = v.u;
    u += 0x7FFFu + ((u >> 16) & 1u);   // RNE
    return (unsigned short)(u >> 16);
}
__device__ __forceinline__ float bflo(unsigned u) {
    union { unsigned u; float f; } v; v.u = u << 16; return v.f;
}
__device__ __forceinline__ float bfhi(unsigned u) {
    union { unsigned u; float f; } v; v.u = u & 0xffff0000u; return v.f;
}
__device__ __forceinline__ float bf2f(ushort u) {
    union { unsigned u; float f; } v; v.u = ((unsigned)u) << 16; return v.f;
}
__device__ __forceinline__ int sig(int p) {            // sigma: acc-layout k-permutation
    return (((p >> 2) & 1) << 4) | (((p >> 3) & 3) << 2) | (p & 3);
}

// ---------------- K0: one-time weight/x transforms ----------------
// wqb: plain bf16 copy of in_proj_w (natural layout, for k_qkv).
// wobs: LDS image of out_w: [row][slot16] with slot ^= (row&7) pre-applied.
// w1s:  per-32-row chunk LDS image of w1 with sigma on columns AND slot-xor.
// w2t:  per-chunk chunk-major transpose of w2 with sigma on hidden cols.
__global__ __launch_bounds__(256) void k_prep(
        const float* __restrict__ ipw, const float* __restrict__ ow,
        const float* __restrict__ w1, const float* __restrict__ w2,
        const float* __restrict__ x,
        ushort* __restrict__ wqb, ushort* __restrict__ wobs,
        ushort* __restrict__ w1s, ushort* __restrict__ w2t,
        ushort* __restrict__ xb, int nx) {
    int i = blockIdx.x * 256 + threadIdx.x;
    if (i < 49152) wqb[i] = f2bf(ipw[i]);
    if (i < 16384) {                    // wobs: i = r*128 + k16*8 + e
        int r = i >> 7, k16 = (i >> 3) & 15, e = i & 7;
        wobs[i] = f2bf(ow[r*128 + ((k16 ^ (r & 7)) << 3) + e]);
    }
    if (i < 65536) {
        // w1s: i = kb*4096 + r*128 + k16*8 + e  (r in [0,32))
        {
            int kb = i >> 12, r = (i >> 7) & 31, k16 = (i >> 3) & 15, e = i & 7;
            int cp = ((k16 ^ (r & 7)) << 3) + e;
            int cs = (cp & ~31) | sig(cp & 31);
            w1s[i] = f2bf(w1[(kb*32 + r)*128 + cs]);
        }
        // w2t: i = kb*4096 + chunk*1024 + row*8 + e
        {
            int kb = i >> 12, chunk = (i >> 10) & 3, row = (i >> 3) & 127, e = i & 7;
            w2t[i] = f2bf(w2[row*512 + kb*32 + sig(chunk*8 + e)]);
        }
    }
    int stride = gridDim.x * 256 * 4;
    for (int j = i * 4; j < nx; j += stride) {
        f32x4 v = *(const f32x4*)(x + j);
        uint2 o;
        o.x = (unsigned)f2bf(v[0]) | ((unsigned)f2bf(v[1]) << 16);
        o.y = (unsigned)f2bf(v[2]) | ((unsigned)f2bf(v[3]) << 16);
        *(uint2*)(xb + j) = o;
    }
}

// ---------------- K1: qkv = x @ in_proj_w^T + b (unchanged) ----------------
__global__ __launch_bounds__(256) void k_qkv(
        const ushort* __restrict__ xb, const ushort* __restrict__ w,
        const float* __restrict__ bias, ushort* __restrict__ qkv, int N) {
    const int wave = threadIdx.x >> 6, lane = threadIdx.x & 63;
    const int l16 = lane & 15, l4 = lane >> 4;
    const int base = blockIdx.x * 64;

    short8 af[4][4];
    #pragma unroll
    for (int mt = 0; mt < 4; ++mt) {
        int row = base + mt*16 + l16;
        int rc = row < N ? row : N - 1;
        const ushort* p = xb + (size_t)rc*128 + l4*8;
        #pragma unroll
        for (int kb = 0; kb < 4; ++kb) af[mt][kb] = *(const short8*)(p + kb*32);
    }
    #pragma unroll
    for (int i = 0; i < 6; ++i) {
        int col = (wave*6 + i)*16 + l16;
        const ushort* pw = w + (size_t)col*128 + l4*8;
        short8 bf[4];
        #pragma unroll
        for (int kb = 0; kb < 4; ++kb) bf[kb] = *(const short8*)(pw + kb*32);
        float bv = bias[col];
        #pragma unroll
        for (int mt = 0; mt < 4; ++mt) {
            f32x4 acc = {0.f, 0.f, 0.f, 0.f};
            #pragma unroll
            for (int kb = 0; kb < 4; ++kb)
                acc = __builtin_amdgcn_mfma_f32_16x16x32_bf16(af[mt][kb], bf[kb], acc, 0, 0, 0);
            #pragma unroll
            for (int r = 0; r < 4; ++r) {
                int row = base + mt*16 + l4*4 + r;
                if (row < N) qkv[(size_t)row*384 + col] = f2bf(acc[r] + bv);
            }
        }
    }
}

// ---------------- K2: sampled attention (unchanged, gather-bound) ----------
__global__ __launch_bounds__(256) void k_attn(
        ushort* __restrict__ qkv, const int* __restrict__ samp, int N) {
    __shared__ float aw[4][8][17];              // [wave][head][k], padded
    __shared__ int   ai[4][16];                 // [wave][k] sample idx
    const int wave = threadIdx.x >> 6, lane = threadIdx.x & 63;
    const int n = blockIdx.x * 4 + wave;
    if (n >= N) return;
    const int k  = lane & 15;
    const int hp = lane >> 4;
    const int h0 = hp, h1 = hp + 4;

    const int idx = samp[(size_t)n*16 + k];
    const ushort* qrow = qkv + (size_t)n*384;
    const ushort* krow = qkv + (size_t)idx*384 + 128;

    float s0 = 0.f, s1 = 0.f;
    {
        const uint4* qa = (const uint4*)(qrow + h0*16);
        const uint4* ka = (const uint4*)(krow + h0*16);
        const uint4* qb = (const uint4*)(qrow + h1*16);
        const uint4* kb = (const uint4*)(krow + h1*16);
        #pragma unroll
        for (int i = 0; i < 2; ++i) {
            uint4 ua = qa[i], va = ka[i], ub = qb[i], vb = kb[i];
            s0 += bflo(ua.x)*bflo(va.x) + bfhi(ua.x)*bfhi(va.x)
                + bflo(ua.y)*bflo(va.y) + bfhi(ua.y)*bfhi(va.y)
                + bflo(ua.z)*bflo(va.z) + bfhi(ua.z)*bfhi(va.z)
                + bflo(ua.w)*bflo(va.w) + bfhi(ua.w)*bfhi(va.w);
            s1 += bflo(ub.x)*bflo(vb.x) + bfhi(ub.x)*bfhi(vb.x)
                + bflo(ub.y)*bflo(vb.y) + bfhi(ub.y)*bfhi(vb.y)
                + bflo(ub.z)*bflo(vb.z) + bfhi(ub.z)*bfhi(vb.z)
                + bflo(ub.w)*bflo(vb.w) + bfhi(ub.w)*bfhi(vb.w);
        }
    }
    s0 *= 0.25f; s1 *= 0.25f;     // 1/sqrt(16)
    float m0 = s0, m1 = s1;
    #pragma unroll
    for (int off = 1; off < 16; off <<= 1) {
        m0 = fmaxf(m0, __shfl_xor(m0, off));
        m1 = fmaxf(m1, __shfl_xor(m1, off));
    }
    float e0 = __expf(s0 - m0), e1 = __expf(s1 - m1);
    float d0 = e0, d1 = e1;
    #pragma unroll
    for (int off = 1; off < 16; off <<= 1) {
        d0 += __shfl_xor(d0, off);
        d1 += __shfl_xor(d1, off);
    }
    aw[wave][h0][k] = e0 / d0;
    aw[wave][h1][k] = e1 / d1;
    if (hp == 0) ai[wave][k] = idx;

    // ---- phase 2 ----
    const int c = lane & 15;        // 16B chunk of the 256B V row
    const int g = lane >> 4;        // k-group
    const int h = c >> 1;           // head owning dims c*8..c*8+7
    const ushort* vt = qkv + 256;   // V region base

    int rows[4];
    #pragma unroll
    for (int b = 0; b < 4; ++b) rows[b] = ai[wave][g + b*4];
    uint4 vv[4];
    #pragma unroll
    for (int b = 0; b < 4; ++b)
        vv[b] = *(const uint4*)(vt + (size_t)(unsigned)rows[b]*384 + c*8);
    float wk[4];
    #pragma unroll
    for (int b = 0; b < 4; ++b) wk[b] = aw[wave][h][g + b*4];

    float a8[8] = {0.f,0.f,0.f,0.f,0.f,0.f,0.f,0.f};
    #pragma unroll
    for (int b = 0; b < 4; ++b) {
        a8[0] = fmaf(wk[b], bflo(vv[b].x), a8[0]);
        a8[1] = fmaf(wk[b], bfhi(vv[b].x), a8[1]);
        a8[2] = fmaf(wk[b], bflo(vv[b].y), a8[2]);
        a8[3] = fmaf(wk[b], bfhi(vv[b].y), a8[3]);
        a8[4] = fmaf(wk[b], bflo(vv[b].z), a8[4]);
        a8[5] = fmaf(wk[b], bfhi(vv[b].z), a8[5]);
        a8[6] = fmaf(wk[b], bflo(vv[b].w), a8[6]);
        a8[7] = fmaf(wk[b], bfhi(vv[b].w), a8[7]);
    }
    #pragma unroll
    for (int i = 0; i < 8; ++i) {
        a8[i] += __shfl_xor(a8[i], 16);
        a8[i] += __shfl_xor(a8[i], 32);
    }
    if (lane < 16) {
        uint4 pack;
        pack.x = (unsigned)f2bf(a8[0]) | ((unsigned)f2bf(a8[1]) << 16);
        pack.y = (unsigned)f2bf(a8[2]) | ((unsigned)f2bf(a8[3]) << 16);
        pack.z = (unsigned)f2bf(a8[4]) | ((unsigned)f2bf(a8[5]) << 16);
        pack.w = (unsigned)f2bf(a8[6]) | ((unsigned)f2bf(a8[7]) << 16);
        *(uint4*)(qkv + (size_t)n*384 + c*8) = pack;   // ctx into dead Q region
    }
}

// ---------------- K3: fused tail, LDS-shared weights, 2-phase dbuf --------
// Swapped MFMAs (D row = token row). Weights staged ONCE per block into LDS:
// wob 32KB (dies after oproj, reused as buffer B), FFN chunks 16KB dbuf.
// Reg-stage: issue loads at top of kb, ds_write after compute (T14).
__global__ __launch_bounds__(256) void k_tail(
        const ushort* __restrict__ ctx, const float* __restrict__ ob,
        const ushort* __restrict__ xb,
        const float* __restrict__ g1, const float* __restrict__ be1,
        const ushort* __restrict__ wobs, const ushort* __restrict__ w1s,
        const float* __restrict__ b1, const ushort* __restrict__ w2t,
        const float* __restrict__ b2,
        const float* __restrict__ g2, const float* __restrict__ be2,
        float* __restrict__ out, int N) {
    __shared__ __align__(16) char smem[49152];   // [0,32K) wob / bufB; [32K,48K) bufA
    const int tid = threadIdx.x;
    const int wave = tid >> 6, lane = tid & 63;
    const int l16 = lane & 15, l4 = lane >> 4;
    const int base = blockIdx.x * 128 + wave * 32;
    int row[2], rc[2];
    row[0] = base + l16;       rc[0] = row[0] < N ? row[0] : N - 1;
    row[1] = base + 16 + l16;  rc[1] = row[1] < N ? row[1] : N - 1;

    // ---- prologue staging: wob (8 slots/thr) + kb0 chunk (4 slots/thr) ----
    {
        uint4 st[8], c0[4];
        const uint4* wo4 = (const uint4*)wobs;
        #pragma unroll
        for (int j = 0; j < 8; ++j) st[j] = wo4[j*256 + tid];
        const uint4* w14 = (const uint4*)w1s;
        const uint4* w24 = (const uint4*)w2t;
        c0[0] = w14[tid]; c0[1] = w14[256 + tid];
        c0[2] = w24[tid]; c0[3] = w24[256 + tid];
        #pragma unroll
        for (int j = 0; j < 8; ++j) *(uint4*)(smem + (j*256 + tid)*16) = st[j];
        *(uint4*)(smem + 32768 + tid*16)               = c0[0];
        *(uint4*)(smem + 32768 + (256 + tid)*16)       = c0[1];
        *(uint4*)(smem + 32768 + 8192 + tid*16)        = c0[2];
        *(uint4*)(smem + 32768 + 8192 + (256 + tid)*16) = c0[3];
    }
    __syncthreads();

    // ---- ctx fragments ----
    short8 cf[2][4];
    #pragma unroll
    for (int mt = 0; mt < 2; ++mt)
        #pragma unroll
        for (int c = 0; c < 4; ++c)
            cf[mt][c] = *(const short8*)(ctx + (size_t)rc[mt]*384 + c*32 + l4*8);

    // ---- out-proj (wob from LDS) + bias + x residual ----
    f32x4 yv[2][8];
    float sum0 = 0.f, sq0 = 0.f, sum1 = 0.f, sq1 = 0.f;
    #pragma unroll
    for (int nt = 0; nt < 8; ++nt) {
        f32x4 a0 = {0.f,0.f,0.f,0.f}, a1 = {0.f,0.f,0.f,0.f};
        #pragma unroll
        for (int c = 0; c < 4; ++c) {
            int rowi = nt*16 + l16;
            int slot = (c*4 + l4) ^ (l16 & 7);
            short8 wf = *(const short8*)(smem + rowi*256 + slot*16);
            a0 = __builtin_amdgcn_mfma_f32_16x16x32_bf16(wf, cf[0][c], a0, 0, 0, 0);
            a1 = __builtin_amdgcn_mfma_f32_16x16x32_bf16(wf, cf[1][c], a1, 0, 0, 0);
        }
        f32x4 obv = *(const f32x4*)(ob + nt*16 + l4*4);
        uint2 xr0 = *(const uint2*)(xb + (size_t)rc[0]*128 + nt*16 + l4*4);
        uint2 xr1 = *(const uint2*)(xb + (size_t)rc[1]*128 + nt*16 + l4*4);
        yv[0][nt][0] = a0[0] + obv[0] + bflo(xr0.x);
        yv[0][nt][1] = a0[1] + obv[1] + bfhi(xr0.x);
        yv[0][nt][2] = a0[2] + obv[2] + bflo(xr0.y);
        yv[0][nt][3] = a0[3] + obv[3] + bfhi(xr0.y);
        yv[1][nt][0] = a1[0] + obv[0] + bflo(xr1.x);
        yv[1][nt][1] = a1[1] + obv[1] + bfhi(xr1.x);
        yv[1][nt][2] = a1[2] + obv[2] + bflo(xr1.y);
        yv[1][nt][3] = a1[3] + obv[3] + bfhi(xr1.y);
        #pragma unroll
        for (int r = 0; r < 4; ++r) {
            sum0 += yv[0][nt][r]; sq0 += yv[0][nt][r]*yv[0][nt][r];
            sum1 += yv[1][nt][r]; sq1 += yv[1][nt][r]*yv[1][nt][r];
        }
    }
    sum0 += __shfl_xor(sum0, 16); sum0 += __shfl_xor(sum0, 32);
    sq0  += __shfl_xor(sq0, 16);  sq0  += __shfl_xor(sq0, 32);
    sum1 += __shfl_xor(sum1, 16); sum1 += __shfl_xor(sum1, 32);
    sq1  += __shfl_xor(sq1, 16);  sq1  += __shfl_xor(sq1, 32);
    float mean[2], rstd[2];
    mean[0] = sum0 * (1.f/128.f);
    rstd[0] = rsqrtf(sq0*(1.f/128.f) - mean[0]*mean[0] + EPS);
    mean[1] = sum1 * (1.f/128.f);
    rstd[1] = rsqrtf(sq1*(1.f/128.f) - mean[1]*mean[1] + EPS);

    // ---- LN1 -> packed bf16 y fragments (k-order = sigma) ----
    short8 yfrag[2][4];
    #pragma unroll
    for (int nt = 0; nt < 8; ++nt) {
        f32x4 gv = *(const f32x4*)(g1 + nt*16 + l4*4);
        f32x4 bv = *(const f32x4*)(be1 + nt*16 + l4*4);
        #pragma unroll
        for (int mt = 0; mt < 2; ++mt)
            #pragma unroll
            for (int r = 0; r < 4; ++r) {
                float yn = (yv[mt][nt][r] - mean[mt]) * rstd[mt] * gv[r] + bv[r];
                yfrag[mt][nt >> 1][(nt & 1)*4 + r] = (short)f2bf(yn);
            }
    }
    __syncthreads();   // all waves done reading wob before bufB (same LDS) is written

    // ---- FFN: 16 kb chunks, LDS double-buffer, reg-staged prefetch ----
    f32x4 acc2[2][8];
    #pragma unroll
    for (int mt = 0; mt < 2; ++mt)
        #pragma unroll
        for (int nt = 0; nt < 8; ++nt) acc2[mt][nt] = (f32x4){0.f,0.f,0.f,0.f};

    #pragma unroll 2
    for (int kb = 0; kb < 16; ++kb) {
        char* cur = smem + ((kb & 1) ? 0 : 32768);
        char* nxt = smem + ((kb & 1) ? 32768 : 0);
        uint4 nx0, nx1, nx2, nx3;
        if (kb < 15) {           // issue next-chunk loads early (hide under compute)
            const uint4* w14 = (const uint4*)(w1s + (kb + 1)*4096);
            const uint4* w24 = (const uint4*)(w2t + (kb + 1)*4096);
            nx0 = w14[tid]; nx1 = w14[256 + tid];
            nx2 = w24[tid]; nx3 = w24[256 + tid];
        }
        // stage-1: hidden rows kb*32..+32 from LDS
        short8 wA[4], wB[4];
        #pragma unroll
        for (int c = 0; c < 4; ++c) {
            int slot = (c*4 + l4) ^ (l16 & 7);
            wA[c] = *(const short8*)(cur + l16*256 + slot*16);
            wB[c] = *(const short8*)(cur + 4096 + l16*256 + slot*16);
        }
        f32x4 hA[2] = {{0.f,0.f,0.f,0.f},{0.f,0.f,0.f,0.f}};
        f32x4 hB[2] = {{0.f,0.f,0.f,0.f},{0.f,0.f,0.f,0.f}};
        #pragma unroll
        for (int c = 0; c < 4; ++c)
            #pragma unroll
            for (int mt = 0; mt < 2; ++mt) {
                hA[mt] = __builtin_amdgcn_mfma_f32_16x16x32_bf16(wA[c], yfrag[mt][c], hA[mt], 0, 0, 0);
                hB[mt] = __builtin_amdgcn_mfma_f32_16x16x32_bf16(wB[c], yfrag[mt][c], hB[mt], 0, 0, 0);
            }
        f32x4 bA = *(const f32x4*)(b1 + kb*32 + l4*4);
        f32x4 bB = *(const f32x4*)(b1 + kb*32 + 16 + l4*4);
        short8 hf[2];
        #pragma unroll
        for (int mt = 0; mt < 2; ++mt)
            #pragma unroll
            for (int r = 0; r < 4; ++r) {
                float vA = hA[mt][r] + bA[r]; vA = vA > 0.f ? vA : 0.f;
                float vB = hB[mt][r] + bB[r]; vB = vB > 0.f ? vB : 0.f;
                hf[mt][r]     = (short)f2bf(vA);
                hf[mt][4 + r] = (short)f2bf(vB);
            }
        // stage-2: w2 chunk from LDS (chunk-major, conflict-free)
        #pragma unroll
        for (int nt = 0; nt < 8; ++nt) {
            short8 w2f = *(const short8*)(cur + 8192 + l4*2048 + (nt*16 + l16)*16);
            acc2[0][nt] = __builtin_amdgcn_mfma_f32_16x16x32_bf16(w2f, hf[0], acc2[0][nt], 0, 0, 0);
            acc2[1][nt] = __builtin_amdgcn_mfma_f32_16x16x32_bf16(w2f, hf[1], acc2[1][nt], 0, 0, 0);
        }
        if (kb < 15) {           // write-late (vmcnt wait lands after compute)
            *(uint4*)(nxt + tid*16)               = nx0;
            *(uint4*)(nxt + (256 + tid)*16)       = nx1;
            *(uint4*)(nxt + 8192 + tid*16)        = nx2;
            *(uint4*)(nxt + 8192 + (256 + tid)*16) = nx3;
        }
        __syncthreads();
    }

    // ---- s = y + ff + b2, LN2, coalesced float4 out ----
    #pragma unroll
    for (int mt = 0; mt < 2; ++mt) {
        float sum2 = 0.f, sq2 = 0.f;
        #pragma unroll
        for (int nt = 0; nt < 8; ++nt) {
            f32x4 b2v = *(const f32x4*)(b2 + nt*16 + l4*4);
            #pragma unroll
            for (int r = 0; r < 4; ++r) {
                float s = bf2f((ushort)yfrag[mt][nt >> 1][(nt & 1)*4 + r]) + acc2[mt][nt][r] + b2v[r];
                acc2[mt][nt][r] = s; sum2 += s; sq2 += s*s;
            }
        }
        sum2 += __shfl_xor(sum2, 16); sum2 += __shfl_xor(sum2, 32);
        sq2  += __shfl_xor(sq2, 16);  sq2  += __shfl_xor(sq2, 32);
        float mean2 = sum2 * (1.f/128.f);
        float rstd2 = rsqrtf(sq2*(1.f/128.f) - mean2*mean2 + EPS);
        if (row[mt] < N) {
            #pragma unroll
            for (int nt = 0; nt < 8; ++nt) {
                f32x4 gv = *(const f32x4*)(g2 + nt*16 + l4*4);
                f32x4 bv = *(const f32x4*)(be2 + nt*16 + l4*4);
                f32x4 o;
                #pragma unroll
                for (int r = 0; r < 4; ++r)
                    o[r] = (acc2[mt][nt][r] - mean2) * rstd2 * gv[r] + bv[r];
                *(f32x4*)(out + (size_t)row[mt]*128 + nt*16 + l4*4) = o;
            }
        }
    }
}

extern "C" void kernel_launch(void* const* d_in, const int* in_sizes, int n_in,
                              void* d_out, int out_size, void* d_ws, size_t ws_size,
                              hipStream_t stream) {
    (void)n_in; (void)out_size; (void)ws_size;
    const float* x   = (const float*)d_in[0];
    const int*   smp = (const int*)  d_in[1];
    const float* ipw = (const float*)d_in[2];
    const float* ipb = (const float*)d_in[3];
    const float* ow  = (const float*)d_in[4];
    const float* ob  = (const float*)d_in[5];
    const float* w1  = (const float*)d_in[6];
    const float* b1  = (const float*)d_in[7];
    const float* w2  = (const float*)d_in[8];
    const float* b2  = (const float*)d_in[9];
    const float* g1  = (const float*)d_in[10];
    const float* be1 = (const float*)d_in[11];
    const float* g2  = (const float*)d_in[12];
    const float* be2 = (const float*)d_in[13];
    const int N = in_sizes[0] / 128;

    ushort* qkv  = (ushort*)d_ws;                   // [N][384] bf16; Q region reused as ctx
    ushort* wqb  = qkv + (size_t)N * 384;           // 384*128 natural
    ushort* wobs = wqb + 384*128;                   // 128*128 LDS image (slot-xor)
    ushort* w1s  = wobs + 128*128;                  // 512*128 LDS image (sigma + slot-xor)
    ushort* w2t  = w1s + 512*128;                   // 128*512 chunk-major (sigma)
    ushort* xb   = w2t + 128*512;                   // [N][128] bf16 x
    float*  outp = (float*)d_out;

    const int nb = (N + 63) / 64;
    k_prep <<<12500,       256, 0, stream>>>(ipw, ow, w1, w2, x, wqb, wobs, w1s, w2t, xb, N*128);
    k_qkv  <<<nb,          256, 0, stream>>>(xb, wqb, ipb, qkv, N);
    k_attn <<<(N+3)/4,     256, 0, stream>>>(qkv, smp, N);
    k_tail <<<(N+127)/128, 256, 0, stream>>>(qkv, ob, xb, g1, be1,
                                             wobs, w1s, b1, w2t, b2, g2, be2, outp, N);
}

// Round 8
// 220.649 us; speedup vs baseline: 2.1047x; 1.2122x over previous
//
#include <hip/hip_runtime.h>
#include <hip/hip_bf16.h>

typedef __attribute__((ext_vector_type(8))) short short8;
typedef __attribute__((ext_vector_type(4))) float f32x4;
typedef __attribute__((ext_vector_type(2))) float f32x2;

#define EPS 1e-5f

__device__ __forceinline__ unsigned short f2bf(float f) {
    union { float f; unsigned u; } v; v.f = f;
    unsigned u = v.u;
    u += 0x7FFFu + ((u >> 16) & 1u);   // RNE
    return (unsigned short)(u >> 16);
}
__device__ __forceinline__ float bflo(unsigned u) {
    union { unsigned u; float f; } v; v.u = u << 16; return v.f;
}
__device__ __forceinline__ float bfhi(unsigned u) {
    union { unsigned u; float f; } v; v.u = u & 0xffff0000u; return v.f;
}
__device__ __forceinline__ float bf2f(ushort u) {
    union { unsigned u; float f; } v; v.u = ((unsigned)u) << 16; return v.f;
}
__device__ __forceinline__ unsigned char f2fp8(float v) {
    return (unsigned char)(__builtin_amdgcn_cvt_pk_fp8_f32(v, v, 0, false) & 0xff);
}
__device__ __forceinline__ int sig(int p) {            // sigma: acc-layout k-permutation
    return (((p >> 2) & 1) << 4) | (((p >> 3) & 3) << 2) | (p & 3);
}

// dot(q[0..16) bf16, k[0..16) fp8) for one head
__device__ __forceinline__ float dot16_q_k8(const ushort* q, const unsigned char* kp) {
    uint4 kw = *(const uint4*)kp;
    const unsigned* qd = (const unsigned*)q;   // 8 dwords of bf16 pairs
    f32x2 a, b; float s = 0.f;
    a = __builtin_amdgcn_cvt_pk_f32_fp8(kw.x, false);
    b = __builtin_amdgcn_cvt_pk_f32_fp8(kw.x, true);
    s += a[0]*bflo(qd[0]) + a[1]*bfhi(qd[0]) + b[0]*bflo(qd[1]) + b[1]*bfhi(qd[1]);
    a = __builtin_amdgcn_cvt_pk_f32_fp8(kw.y, false);
    b = __builtin_amdgcn_cvt_pk_f32_fp8(kw.y, true);
    s += a[0]*bflo(qd[2]) + a[1]*bfhi(qd[2]) + b[0]*bflo(qd[3]) + b[1]*bfhi(qd[3]);
    a = __builtin_amdgcn_cvt_pk_f32_fp8(kw.z, false);
    b = __builtin_amdgcn_cvt_pk_f32_fp8(kw.z, true);
    s += a[0]*bflo(qd[4]) + a[1]*bfhi(qd[4]) + b[0]*bflo(qd[5]) + b[1]*bfhi(qd[5]);
    a = __builtin_amdgcn_cvt_pk_f32_fp8(kw.w, false);
    b = __builtin_amdgcn_cvt_pk_f32_fp8(kw.w, true);
    s += a[0]*bflo(qd[6]) + a[1]*bfhi(qd[6]) + b[0]*bflo(qd[7]) + b[1]*bfhi(qd[7]);
    return s;
}

// ---------------- K0: one-time weight/x transforms (unchanged) -------------
__global__ __launch_bounds__(256) void k_prep(
        const float* __restrict__ ipw, const float* __restrict__ ow,
        const float* __restrict__ w1, const float* __restrict__ w2,
        const float* __restrict__ x,
        ushort* __restrict__ wqb, ushort* __restrict__ wobs,
        ushort* __restrict__ w1s, ushort* __restrict__ w2t,
        ushort* __restrict__ xb, int nx) {
    int i = blockIdx.x * 256 + threadIdx.x;
    if (i < 49152) wqb[i] = f2bf(ipw[i]);
    if (i < 16384) {                    // wobs: i = r*128 + k16*8 + e
        int r = i >> 7, k16 = (i >> 3) & 15, e = i & 7;
        wobs[i] = f2bf(ow[r*128 + ((k16 ^ (r & 7)) << 3) + e]);
    }
    if (i < 65536) {
        {
            int kb = i >> 12, r = (i >> 7) & 31, k16 = (i >> 3) & 15, e = i & 7;
            int cp = ((k16 ^ (r & 7)) << 3) + e;
            int cs = (cp & ~31) | sig(cp & 31);
            w1s[i] = f2bf(w1[(kb*32 + r)*128 + cs]);
        }
        {
            int kb = i >> 12, chunk = (i >> 10) & 3, row = (i >> 3) & 127, e = i & 7;
            w2t[i] = f2bf(w2[row*512 + kb*32 + sig(chunk*8 + e)]);
        }
    }
    int stride = gridDim.x * 256 * 4;
    for (int j = i * 4; j < nx; j += stride) {
        f32x4 v = *(const f32x4*)(x + j);
        uint2 o;
        o.x = (unsigned)f2bf(v[0]) | ((unsigned)f2bf(v[1]) << 16);
        o.y = (unsigned)f2bf(v[2]) | ((unsigned)f2bf(v[3]) << 16);
        *(uint2*)(xb + j) = o;
    }
}

// ---------------- K1: qkv projection; Q -> bf16 qt, K/V -> fp8 kv8 ---------
__global__ __launch_bounds__(256) void k_qkv(
        const ushort* __restrict__ xb, const ushort* __restrict__ w,
        const float* __restrict__ bias, ushort* __restrict__ qt,
        unsigned char* __restrict__ kv8, int N) {
    const int wave = threadIdx.x >> 6, lane = threadIdx.x & 63;
    const int l16 = lane & 15, l4 = lane >> 4;
    const int base = blockIdx.x * 64;

    short8 af[4][4];
    #pragma unroll
    for (int mt = 0; mt < 4; ++mt) {
        int row = base + mt*16 + l16;
        int rc = row < N ? row : N - 1;
        const ushort* p = xb + (size_t)rc*128 + l4*8;
        #pragma unroll
        for (int kb = 0; kb < 4; ++kb) af[mt][kb] = *(const short8*)(p + kb*32);
    }
    #pragma unroll
    for (int i = 0; i < 6; ++i) {
        int col = (wave*6 + i)*16 + l16;
        const ushort* pw = w + (size_t)col*128 + l4*8;
        short8 bf[4];
        #pragma unroll
        for (int kb = 0; kb < 4; ++kb) bf[kb] = *(const short8*)(pw + kb*32);
        float bv = bias[col];
        #pragma unroll
        for (int mt = 0; mt < 4; ++mt) {
            f32x4 acc = {0.f, 0.f, 0.f, 0.f};
            #pragma unroll
            for (int kb = 0; kb < 4; ++kb)
                acc = __builtin_amdgcn_mfma_f32_16x16x32_bf16(af[mt][kb], bf[kb], acc, 0, 0, 0);
            #pragma unroll
            for (int r = 0; r < 4; ++r) {
                int row = base + mt*16 + l4*4 + r;
                if (row < N) {
                    float v = acc[r] + bv;
                    if (col < 128) qt[(size_t)row*128 + col] = f2bf(v);
                    else kv8[(size_t)row*256 + (col - 128)] = f2fp8(v);
                }
            }
        }
    }
}

// ---------------- K2: sampled attention, fp8 K/V gather --------------------
// Phase 1: lane=(k, hp) -> softmax weights (K row = 128B fp8 gather).
// Phase 2: lane=(g, c) -> V gather (128B fp8 rows), 4 rows per uint2 load inst.
// ctx (bf16) overwrites the dead q table rows.
__global__ __launch_bounds__(256) void k_attn(
        ushort* __restrict__ qt, const unsigned char* __restrict__ kv8,
        const int* __restrict__ samp, int N) {
    __shared__ float aw[4][8][17];              // [wave][head][k], padded
    __shared__ int   ai[4][16];                 // [wave][k] sample idx
    const int wave = threadIdx.x >> 6, lane = threadIdx.x & 63;
    const int n = blockIdx.x * 4 + wave;
    if (n >= N) return;
    const int k  = lane & 15;
    const int hp = lane >> 4;
    const int h0 = hp, h1 = hp + 4;

    const int idx = samp[(size_t)n*16 + k];
    const ushort* qrow = qt + (size_t)n*128;
    const unsigned char* krow = kv8 + (size_t)idx*256;

    float s0 = dot16_q_k8(qrow + h0*16, krow + h0*16);
    float s1 = dot16_q_k8(qrow + h1*16, krow + h1*16);
    s0 *= 0.25f; s1 *= 0.25f;     // 1/sqrt(16)
    float m0 = s0, m1 = s1;
    #pragma unroll
    for (int off = 1; off < 16; off <<= 1) {
        m0 = fmaxf(m0, __shfl_xor(m0, off));
        m1 = fmaxf(m1, __shfl_xor(m1, off));
    }
    float e0 = __expf(s0 - m0), e1 = __expf(s1 - m1);
    float d0 = e0, d1 = e1;
    #pragma unroll
    for (int off = 1; off < 16; off <<= 1) {
        d0 += __shfl_xor(d0, off);
        d1 += __shfl_xor(d1, off);
    }
    aw[wave][h0][k] = e0 / d0;
    aw[wave][h1][k] = e1 / d1;
    if (hp == 0) ai[wave][k] = idx;

    // ---- phase 2: lane=(g=lane>>4, c=lane&15); chunk c = 8B of 128B V row ----
    const int c = lane & 15;
    const int g = lane >> 4;
    const int h = c >> 1;           // head owning dims c*8..c*8+7

    int rows[4];
    #pragma unroll
    for (int b = 0; b < 4; ++b) rows[b] = ai[wave][g + b*4];
    uint2 vv[4];
    #pragma unroll
    for (int b = 0; b < 4; ++b)
        vv[b] = *(const uint2*)(kv8 + (size_t)(unsigned)rows[b]*256 + 128 + c*8);
    float wk[4];
    #pragma unroll
    for (int b = 0; b < 4; ++b) wk[b] = aw[wave][h][g + b*4];

    float a8[8] = {0.f,0.f,0.f,0.f,0.f,0.f,0.f,0.f};
    #pragma unroll
    for (int b = 0; b < 4; ++b) {
        f32x2 p;
        p = __builtin_amdgcn_cvt_pk_f32_fp8(vv[b].x, false);
        a8[0] = fmaf(wk[b], p[0], a8[0]); a8[1] = fmaf(wk[b], p[1], a8[1]);
        p = __builtin_amdgcn_cvt_pk_f32_fp8(vv[b].x, true);
        a8[2] = fmaf(wk[b], p[0], a8[2]); a8[3] = fmaf(wk[b], p[1], a8[3]);
        p = __builtin_amdgcn_cvt_pk_f32_fp8(vv[b].y, false);
        a8[4] = fmaf(wk[b], p[0], a8[4]); a8[5] = fmaf(wk[b], p[1], a8[5]);
        p = __builtin_amdgcn_cvt_pk_f32_fp8(vv[b].y, true);
        a8[6] = fmaf(wk[b], p[0], a8[6]); a8[7] = fmaf(wk[b], p[1], a8[7]);
    }
    #pragma unroll
    for (int i = 0; i < 8; ++i) {
        a8[i] += __shfl_xor(a8[i], 16);
        a8[i] += __shfl_xor(a8[i], 32);
    }
    if (lane < 16) {
        uint4 pack;
        pack.x = (unsigned)f2bf(a8[0]) | ((unsigned)f2bf(a8[1]) << 16);
        pack.y = (unsigned)f2bf(a8[2]) | ((unsigned)f2bf(a8[3]) << 16);
        pack.z = (unsigned)f2bf(a8[4]) | ((unsigned)f2bf(a8[5]) << 16);
        pack.w = (unsigned)f2bf(a8[6]) | ((unsigned)f2bf(a8[7]) << 16);
        *(uint4*)(qt + (size_t)n*128 + c*8) = pack;   // ctx over dead q row
    }
}

// ---------------- K3: fused tail, LDS-shared weights, 2-phase dbuf ---------
__global__ __launch_bounds__(256) void k_tail(
        const ushort* __restrict__ ctx, const float* __restrict__ ob,
        const ushort* __restrict__ xb,
        const float* __restrict__ g1, const float* __restrict__ be1,
        const ushort* __restrict__ wobs, const ushort* __restrict__ w1s,
        const float* __restrict__ b1, const ushort* __restrict__ w2t,
        const float* __restrict__ b2,
        const float* __restrict__ g2, const float* __restrict__ be2,
        float* __restrict__ out, int N) {
    __shared__ __align__(16) char smem[49152];   // [0,32K) wob / bufB; [32K,48K) bufA
    const int tid = threadIdx.x;
    const int wave = tid >> 6, lane = tid & 63;
    const int l16 = lane & 15, l4 = lane >> 4;
    const int base = blockIdx.x * 128 + wave * 32;
    int row[2], rc[2];
    row[0] = base + l16;       rc[0] = row[0] < N ? row[0] : N - 1;
    row[1] = base + 16 + l16;  rc[1] = row[1] < N ? row[1] : N - 1;

    // ---- prologue staging: wob (8 slots/thr) + kb0 chunk (4 slots/thr) ----
    {
        uint4 st[8], c0[4];
        const uint4* wo4 = (const uint4*)wobs;
        #pragma unroll
        for (int j = 0; j < 8; ++j) st[j] = wo4[j*256 + tid];
        const uint4* w14 = (const uint4*)w1s;
        const uint4* w24 = (const uint4*)w2t;
        c0[0] = w14[tid]; c0[1] = w14[256 + tid];
        c0[2] = w24[tid]; c0[3] = w24[256 + tid];
        #pragma unroll
        for (int j = 0; j < 8; ++j) *(uint4*)(smem + (j*256 + tid)*16) = st[j];
        *(uint4*)(smem + 32768 + tid*16)               = c0[0];
        *(uint4*)(smem + 32768 + (256 + tid)*16)       = c0[1];
        *(uint4*)(smem + 32768 + 8192 + tid*16)        = c0[2];
        *(uint4*)(smem + 32768 + 8192 + (256 + tid)*16) = c0[3];
    }
    __syncthreads();

    // ---- ctx fragments (dense 128-elem rows now) ----
    short8 cf[2][4];
    #pragma unroll
    for (int mt = 0; mt < 2; ++mt)
        #pragma unroll
        for (int c = 0; c < 4; ++c)
            cf[mt][c] = *(const short8*)(ctx + (size_t)rc[mt]*128 + c*32 + l4*8);

    // ---- out-proj (wob from LDS) + bias + x residual ----
    f32x4 yv[2][8];
    float sum0 = 0.f, sq0 = 0.f, sum1 = 0.f, sq1 = 0.f;
    #pragma unroll
    for (int nt = 0; nt < 8; ++nt) {
        f32x4 a0 = {0.f,0.f,0.f,0.f}, a1 = {0.f,0.f,0.f,0.f};
        #pragma unroll
        for (int c = 0; c < 4; ++c) {
            int rowi = nt*16 + l16;
            int slot = (c*4 + l4) ^ (l16 & 7);
            short8 wf = *(const short8*)(smem + rowi*256 + slot*16);
            a0 = __builtin_amdgcn_mfma_f32_16x16x32_bf16(wf, cf[0][c], a0, 0, 0, 0);
            a1 = __builtin_amdgcn_mfma_f32_16x16x32_bf16(wf, cf[1][c], a1, 0, 0, 0);
        }
        f32x4 obv = *(const f32x4*)(ob + nt*16 + l4*4);
        uint2 xr0 = *(const uint2*)(xb + (size_t)rc[0]*128 + nt*16 + l4*4);
        uint2 xr1 = *(const uint2*)(xb + (size_t)rc[1]*128 + nt*16 + l4*4);
        yv[0][nt][0] = a0[0] + obv[0] + bflo(xr0.x);
        yv[0][nt][1] = a0[1] + obv[1] + bfhi(xr0.x);
        yv[0][nt][2] = a0[2] + obv[2] + bflo(xr0.y);
        yv[0][nt][3] = a0[3] + obv[3] + bfhi(xr0.y);
        yv[1][nt][0] = a1[0] + obv[0] + bflo(xr1.x);
        yv[1][nt][1] = a1[1] + obv[1] + bfhi(xr1.x);
        yv[1][nt][2] = a1[2] + obv[2] + bflo(xr1.y);
        yv[1][nt][3] = a1[3] + obv[3] + bfhi(xr1.y);
        #pragma unroll
        for (int r = 0; r < 4; ++r) {
            sum0 += yv[0][nt][r]; sq0 += yv[0][nt][r]*yv[0][nt][r];
            sum1 += yv[1][nt][r]; sq1 += yv[1][nt][r]*yv[1][nt][r];
        }
    }
    sum0 += __shfl_xor(sum0, 16); sum0 += __shfl_xor(sum0, 32);
    sq0  += __shfl_xor(sq0, 16);  sq0  += __shfl_xor(sq0, 32);
    sum1 += __shfl_xor(sum1, 16); sum1 += __shfl_xor(sum1, 32);
    sq1  += __shfl_xor(sq1, 16);  sq1  += __shfl_xor(sq1, 32);
    float mean[2], rstd[2];
    mean[0] = sum0 * (1.f/128.f);
    rstd[0] = rsqrtf(sq0*(1.f/128.f) - mean[0]*mean[0] + EPS);
    mean[1] = sum1 * (1.f/128.f);
    rstd[1] = rsqrtf(sq1*(1.f/128.f) - mean[1]*mean[1] + EPS);

    // ---- LN1 -> packed bf16 y fragments (k-order = sigma) ----
    short8 yfrag[2][4];
    #pragma unroll
    for (int nt = 0; nt < 8; ++nt) {
        f32x4 gv = *(const f32x4*)(g1 + nt*16 + l4*4);
        f32x4 bv = *(const f32x4*)(be1 + nt*16 + l4*4);
        #pragma unroll
        for (int mt = 0; mt < 2; ++mt)
            #pragma unroll
            for (int r = 0; r < 4; ++r) {
                float yn = (yv[mt][nt][r] - mean[mt]) * rstd[mt] * gv[r] + bv[r];
                yfrag[mt][nt >> 1][(nt & 1)*4 + r] = (short)f2bf(yn);
            }
    }
    __syncthreads();   // all waves done reading wob before bufB is written

    // ---- FFN: 16 kb chunks, LDS double-buffer, reg-staged prefetch ----
    f32x4 acc2[2][8];
    #pragma unroll
    for (int mt = 0; mt < 2; ++mt)
        #pragma unroll
        for (int nt = 0; nt < 8; ++nt) acc2[mt][nt] = (f32x4){0.f,0.f,0.f,0.f};

    #pragma unroll 2
    for (int kb = 0; kb < 16; ++kb) {
        char* cur = smem + ((kb & 1) ? 0 : 32768);
        char* nxt = smem + ((kb & 1) ? 32768 : 0);
        uint4 nx0, nx1, nx2, nx3;
        if (kb < 15) {           // issue next-chunk loads early
            const uint4* w14 = (const uint4*)(w1s + (kb + 1)*4096);
            const uint4* w24 = (const uint4*)(w2t + (kb + 1)*4096);
            nx0 = w14[tid]; nx1 = w14[256 + tid];
            nx2 = w24[tid]; nx3 = w24[256 + tid];
        }
        short8 wA[4], wB[4];
        #pragma unroll
        for (int c = 0; c < 4; ++c) {
            int slot = (c*4 + l4) ^ (l16 & 7);
            wA[c] = *(const short8*)(cur + l16*256 + slot*16);
            wB[c] = *(const short8*)(cur + 4096 + l16*256 + slot*16);
        }
        f32x4 hA[2] = {{0.f,0.f,0.f,0.f},{0.f,0.f,0.f,0.f}};
        f32x4 hB[2] = {{0.f,0.f,0.f,0.f},{0.f,0.f,0.f,0.f}};
        #pragma unroll
        for (int c = 0; c < 4; ++c)
            #pragma unroll
            for (int mt = 0; mt < 2; ++mt) {
                hA[mt] = __builtin_amdgcn_mfma_f32_16x16x32_bf16(wA[c], yfrag[mt][c], hA[mt], 0, 0, 0);
                hB[mt] = __builtin_amdgcn_mfma_f32_16x16x32_bf16(wB[c], yfrag[mt][c], hB[mt], 0, 0, 0);
            }
        f32x4 bA = *(const f32x4*)(b1 + kb*32 + l4*4);
        f32x4 bB = *(const f32x4*)(b1 + kb*32 + 16 + l4*4);
        short8 hf[2];
        #pragma unroll
        for (int mt = 0; mt < 2; ++mt)
            #pragma unroll
            for (int r = 0; r < 4; ++r) {
                float vA = hA[mt][r] + bA[r]; vA = vA > 0.f ? vA : 0.f;
                float vB = hB[mt][r] + bB[r]; vB = vB > 0.f ? vB : 0.f;
                hf[mt][r]     = (short)f2bf(vA);
                hf[mt][4 + r] = (short)f2bf(vB);
            }
        #pragma unroll
        for (int nt = 0; nt < 8; ++nt) {
            short8 w2f = *(const short8*)(cur + 8192 + l4*2048 + (nt*16 + l16)*16);
            acc2[0][nt] = __builtin_amdgcn_mfma_f32_16x16x32_bf16(w2f, hf[0], acc2[0][nt], 0, 0, 0);
            acc2[1][nt] = __builtin_amdgcn_mfma_f32_16x16x32_bf16(w2f, hf[1], acc2[1][nt], 0, 0, 0);
        }
        if (kb < 15) {           // write-late
            *(uint4*)(nxt + tid*16)               = nx0;
            *(uint4*)(nxt + (256 + tid)*16)       = nx1;
            *(uint4*)(nxt + 8192 + tid*16)        = nx2;
            *(uint4*)(nxt + 8192 + (256 + tid)*16) = nx3;
        }
        __syncthreads();
    }

    // ---- s = y + ff + b2, LN2, coalesced float4 out ----
    #pragma unroll
    for (int mt = 0; mt < 2; ++mt) {
        float sum2 = 0.f, sq2 = 0.f;
        #pragma unroll
        for (int nt = 0; nt < 8; ++nt) {
            f32x4 b2v = *(const f32x4*)(b2 + nt*16 + l4*4);
            #pragma unroll
            for (int r = 0; r < 4; ++r) {
                float s = bf2f((ushort)yfrag[mt][nt >> 1][(nt & 1)*4 + r]) + acc2[mt][nt][r] + b2v[r];
                acc2[mt][nt][r] = s; sum2 += s; sq2 += s*s;
            }
        }
        sum2 += __shfl_xor(sum2, 16); sum2 += __shfl_xor(sum2, 32);
        sq2  += __shfl_xor(sq2, 16);  sq2  += __shfl_xor(sq2, 32);
        float mean2 = sum2 * (1.f/128.f);
        float rstd2 = rsqrtf(sq2*(1.f/128.f) - mean2*mean2 + EPS);
        if (row[mt] < N) {
            #pragma unroll
            for (int nt = 0; nt < 8; ++nt) {
                f32x4 gv = *(const f32x4*)(g2 + nt*16 + l4*4);
                f32x4 bv = *(const f32x4*)(be2 + nt*16 + l4*4);
                f32x4 o;
                #pragma unroll
                for (int r = 0; r < 4; ++r)
                    o[r] = (acc2[mt][nt][r] - mean2) * rstd2 * gv[r] + bv[r];
                *(f32x4*)(out + (size_t)row[mt]*128 + nt*16 + l4*4) = o;
            }
        }
    }
}

extern "C" void kernel_launch(void* const* d_in, const int* in_sizes, int n_in,
                              void* d_out, int out_size, void* d_ws, size_t ws_size,
                              hipStream_t stream) {
    (void)n_in; (void)out_size; (void)ws_size;
    const float* x   = (const float*)d_in[0];
    const int*   smp = (const int*)  d_in[1];
    const float* ipw = (const float*)d_in[2];
    const float* ipb = (const float*)d_in[3];
    const float* ow  = (const float*)d_in[4];
    const float* ob  = (const float*)d_in[5];
    const float* w1  = (const float*)d_in[6];
    const float* b1  = (const float*)d_in[7];
    const float* w2  = (const float*)d_in[8];
    const float* b2  = (const float*)d_in[9];
    const float* g1  = (const float*)d_in[10];
    const float* be1 = (const float*)d_in[11];
    const float* g2  = (const float*)d_in[12];
    const float* be2 = (const float*)d_in[13];
    const int N = in_sizes[0] / 128;

    ushort* qt   = (ushort*)d_ws;                   // [N][128] bf16 q, then ctx
    unsigned char* kv8 = (unsigned char*)(qt + (size_t)N*128);  // [N][256] fp8 K|V
    ushort* wqb  = (ushort*)(kv8 + (size_t)N*256);  // 384*128 natural
    ushort* wobs = wqb + 384*128;                   // 128*128 LDS image (slot-xor)
    ushort* w1s  = wobs + 128*128;                  // 512*128 LDS image (sigma+xor)
    ushort* w2t  = w1s + 512*128;                   // 128*512 chunk-major (sigma)
    ushort* xb   = w2t + 128*512;                   // [N][128] bf16 x
    float*  outp = (float*)d_out;

    const int nb = (N + 63) / 64;
    k_prep <<<12500,       256, 0, stream>>>(ipw, ow, w1, w2, x, wqb, wobs, w1s, w2t, xb, N*128);
    k_qkv  <<<nb,          256, 0, stream>>>(xb, wqb, ipb, qt, kv8, N);
    k_attn <<<(N+3)/4,     256, 0, stream>>>(qt, kv8, smp, N);
    k_tail <<<(N+127)/128, 256, 0, stream>>>(qt, ob, xb, g1, be1,
                                             wobs, w1s, b1, w2t, b2, g2, be2, outp, N);
}